// Round 3
// baseline (82.256 us; speedup 1.0000x reference)
//
#include <hip/hip_runtime.h>
#include <math.h>

#define BLOCK 256

// Quotient-ring Horner step over F[l]/(l^3 - pp*l - qq):
// (a0 + a1*l + a2*l^2) * l^2 + bn  ->  (qq*a1 + bn, pp*a1 + qq*a2, a0 + pp*a2)
#define QSTEP(a0, a1, a2, bn)                         \
    {                                                 \
        double n0 = fma(qq, a1, bn);                  \
        double n1 = fma(pp, a1, qq * (a2));           \
        double n2 = fma(pp, a2, a0);                  \
        a0 = n0; a1 = n1; a2 = n2;                    \
    }

__global__ __launch_bounds__(BLOCK, 4) void lie_expm_kernel(const float* __restrict__ v,
                                                            float* __restrict__ out,
                                                            int n) {
    __shared__ float lds[BLOCK * 9];

    int tid = threadIdx.x;
    int gid = blockIdx.x * BLOCK + tid;
    bool active = gid < n;

    if (active) {
        const float4* vv = reinterpret_cast<const float4*>(v);
        float4 p0 = vv[2 * (size_t)gid + 0];
        float4 p1 = vv[2 * (size_t)gid + 1];

        // ---- s selection entirely in fp32 (off the fp64 critical path) ----
        float c0f = fabsf(p0.w + p1.x) + fabsf(p0.z + p1.y) + fabsf(p1.z);
        float c1f = fabsf(p1.y - p0.z) + fabsf(p0.w - p1.x) + fabsf(p1.w);
        float c2f = fabsf(p0.x) + fabsf(p0.y) + 2.0f * fabsf(p0.w);
        float nrmf = fmaxf(c0f, fmaxf(c1f, c2f));
        const float inv_theta13 = (float)(1.0 / 5.371920351148152);
        float rf = nrmf * inv_theta13;
        int s = 0;
        if (rf > 1.0f) {
            int hi = __float_as_int(rf);
            s = ((hi >> 23) & 0xff) - 127 + 1;     // ceil(log2 r) (conservative)
            if (s > 60) s = 60;
        }
        // exact powers of two: 2^-s, 4^-s, 8^-s
        double sc1 = __hiloint2double((1023 - s)     << 20, 0);
        double sc2 = __hiloint2double((1023 - 2 * s) << 20, 0);
        double sc3 = __hiloint2double((1023 - 3 * s) << 20, 0);

        // ---- A as 9 named scalars (the ONLY long-lived fp64 matrix state) ----
        double x0 = p0.x, x1 = p0.y, x2 = p0.z, x3 = p0.w;
        double x4 = p1.x, x5 = p1.y, x6 = p1.z, x7 = p1.w;
        double a00 = x3 + x4,  a01 = x5 - x2,  a02 = x0;
        double a10 = x2 + x5,  a11 = x3 - x4,  a12 = x1;
        double a20 = x6,       a21 = x7,       a22 = -2.0 * x3;

        // Cayley-Hamilton invariants WITHOUT materializing A^2:
        // tr(A^2) = a00^2+a11^2+a22^2 + 2(a01 a10 + a02 a20 + a12 a21)
        double pu = fma(a01, a10, fma(a02, a20, a12 * a21))
                  + 0.5 * fma(a00, a00, fma(a11, a11, a22 * a22));
        double qu = fma(a00, fma(a11, a22, -a12 * a21),
                    fma(-a01, fma(a10, a22, -a12 * a20),
                        a02 * fma(a10, a21, -a11 * a20)));       // det(A)
        double pp = pu * sc2;   // invariants of A/2^s
        double qq = qu * sc3;

        // Pade-13 coefficients
        const double b0  = 64764752532480000.0, b1  = 32382376266240000.0;
        const double b2  = 7771770303897600.0,  b3  = 1187353796428800.0;
        const double b4  = 129060195264000.0,   b5  = 10559470521600.0;
        const double b6  = 670442572800.0,      b7  = 33522128640.0;
        const double b8  = 1323241920.0,        b9  = 40840800.0;
        const double b10 = 960960.0,            b11 = 16380.0;
        const double b12 = 182.0,               b13 = 1.0;

        // Scalar Horner in B = (A/2^s)^2 over the quotient ring
        // (two independent chains -> ILP; only 12 doubles live)
        double u0 = b13, u1 = 0.0, u2 = 0.0;
        QSTEP(u0, u1, u2, b11)
        QSTEP(u0, u1, u2, b9)
        QSTEP(u0, u1, u2, b7)
        QSTEP(u0, u1, u2, b5)
        QSTEP(u0, u1, u2, b3)
        QSTEP(u0, u1, u2, b1)

        double t0 = b12, t1 = 0.0, t2 = 0.0;
        QSTEP(t0, t1, t2, b10)
        QSTEP(t0, t1, t2, b8)
        QSTEP(t0, t1, t2, b6)
        QSTEP(t0, t1, t2, b4)
        QSTEP(t0, t1, t2, b2)
        QSTEP(t0, t1, t2, b0)

        // U = Asc * (u-poly) reduced into the basis
        double U0 = qq * u2;
        double U1 = fma(pp, u2, u0);
        double U2 = u1;

        // M = V - U, R = V + U (triples)
        double a  = t0 - U0, bq = t1 - U1, c  = t2 - U2;
        double r0 = t0 + U0, r1 = t1 + U1, r2 = t2 + U2;

        // Multiply-by-M operator L = [[a,qc,qb],[b,a+pc,pb+qc],[c,b,a+pc]]
        double qc = qq * c;
        double qb = qq * bq;
        double d  = fma(pp, c, a);
        double Le = fma(pp, bq, qc);
        double ad = a * d;
        double fb = qb * bq;
        // e = adj(L)*r, consuming each cofactor immediately (det cancels later)
        double e0 = fma(fma(d, d, -Le * bq), r0,
                    fma(fb - qc * d,         r1,
                        fma(qc, Le, -qb * d) * r2));
        double e1 = fma(fma(Le, c, -bq * d), r0,
                    fma(fma(-qb, c, ad),     r1,
                        (fb - a * Le) * r2));
        double e2 = fma(fma(bq, bq, -d * c), r0,
                    fma(fma(qc, c, -a * bq), r1,
                        fma(-qc, bq, ad) * r2));

        // Overflow guard for the (essentially impossible) s >= 3 case
        if (s >= 3) {
            double det = fma(a, fma(d, d, -Le * bq),
                         fma(qc, fma(Le, c, -bq * d),
                             qb * fma(bq, bq, -d * c)));
            double rd = 1.0 / det;
            e0 *= rd; e1 *= rd; e2 *= rd;
        }

        // Undo scaling: square in the quotient ring (14 flops per step)
        for (int i = 0; i < s; ++i) {
            double d0 = e0 * e0;
            double d1 = 2.0 * e0 * e1;
            double d2 = fma(e1, e1, 2.0 * e0 * e2);
            double d3 = 2.0 * e1 * e2;
            double d4 = e2 * e2;
            e0 = fma(qq, d3, d0);
            e1 = fma(pp, d3, fma(qq, d4, d1));
            e2 = fma(pp, d4, d2);
        }

        // Back to unscaled basis: exp(A) = e0 I + (e1 2^-s) A + (e2 4^-s) A^2
        double e1s = e1 * sc1;
        double e2s = e2 * sc2;

        // Epilogue: A^2 entries computed on the fly, consumed immediately.
        double bsum = fma(a20, a02, fma(a21, a12, a22 * a22));
        double H8 = fma(e2s, bsum, fma(e1s, a22, e0));
#if __has_builtin(__builtin_amdgcn_rcp)
        double invh = __builtin_amdgcn_rcp(H8);
        invh = fma(invh, fma(-H8, invh, 1.0), invh);
        invh = fma(invh, fma(-H8, invh, 1.0), invh);
#else
        double invh = 1.0 / H8;
#endif

        bsum = fma(a00, a00, fma(a01, a10, a02 * a20));
        lds[tid * 9 + 0] = (float)(fma(e2s, bsum, fma(e1s, a00, e0)) * invh);
        bsum = fma(a00, a01, fma(a01, a11, a02 * a21));
        lds[tid * 9 + 1] = (float)(fma(e2s, bsum, e1s * a01) * invh);
        bsum = fma(a00, a02, fma(a01, a12, a02 * a22));
        lds[tid * 9 + 2] = (float)(fma(e2s, bsum, e1s * a02) * invh);
        bsum = fma(a10, a00, fma(a11, a10, a12 * a20));
        lds[tid * 9 + 3] = (float)(fma(e2s, bsum, e1s * a10) * invh);
        bsum = fma(a10, a01, fma(a11, a11, a12 * a21));
        lds[tid * 9 + 4] = (float)(fma(e2s, bsum, fma(e1s, a11, e0)) * invh);
        bsum = fma(a10, a02, fma(a11, a12, a12 * a22));
        lds[tid * 9 + 5] = (float)(fma(e2s, bsum, e1s * a12) * invh);
        bsum = fma(a20, a00, fma(a21, a10, a22 * a20));
        lds[tid * 9 + 6] = (float)(fma(e2s, bsum, e1s * a20) * invh);
        bsum = fma(a20, a01, fma(a21, a11, a22 * a21));
        lds[tid * 9 + 7] = (float)(fma(e2s, bsum, e1s * a21) * invh);
        lds[tid * 9 + 8] = 1.0f;   // H[8]/H[8]
    }
    __syncthreads();

    // coalesced float4 store: block covers BLOCK*9 contiguous floats
    size_t base = (size_t)blockIdx.x * (BLOCK * 9);
    int count = n - blockIdx.x * BLOCK;
    if (count > BLOCK) count = BLOCK;
    int total = count * 9;
    int nf4 = total >> 2;
    float4* out4 = reinterpret_cast<float4*>(out + base);
    const float4* lds4 = reinterpret_cast<const float4*>(lds);
#pragma unroll
    for (int i = 0; i < 3; ++i) {
        int idx = i * BLOCK + tid;
        if (idx < nf4) out4[idx] = lds4[idx];
    }
    // tail (only possible in the last block when total % 4 != 0)
    int remstart = nf4 << 2;
    int ridx = remstart + tid;
    if (ridx < total) out[base + ridx] = lds[ridx];
}

extern "C" void kernel_launch(void* const* d_in, const int* in_sizes, int n_in,
                              void* d_out, int out_size, void* d_ws, size_t ws_size,
                              hipStream_t stream) {
    const float* v = (const float*)d_in[0];
    float* out = (float*)d_out;
    int n = in_sizes[0] / 8;   // B rows of 8 coefficients
    int grid = (n + BLOCK - 1) / BLOCK;
    lie_expm_kernel<<<grid, BLOCK, 0, stream>>>(v, out, n);
}